// Round 16
// baseline (54.262 us; speedup 1.0000x reference)
//
#include <hip/hip_runtime.h>
#include <cstdint>

#define N_ATOMS 16384
#define NBLK 64
#define NTHR 256
#define G 24
#define NCELLS 13824
#define NCELLS_PAD 14336
#define CPT 14                    // cells per thread in k2 (1024 thr)
#define BOX_LO -48.0f
#define INV_CELL 0.25f            // cell side 4.0
#define SINIT 3.0e38f

// ws layout (~540 KB < 590 KB proven):
#define OFF_COUNTS 0              // int[2]: n_ctx, n_gen
#define OFF_BLKGEN 256            // int[64]
#define OFF_BLKGOFF 512           // int[64]
#define OFF_FLAGS 1024            // u64[256] gen bit per atom
#define OFF_ACELL 3072            // u16[16384] per-atom cell (0xFFFF = gen)
#define OFF_POS 35840             // int[16384] ctx scatter position
#define OFF_START 101376          // int[14337] cell starts
#define OFF_GENIDX 158976         // int[16384]
#define OFF_CTX4 224512           // float4[16384] cell-sorted (x,y,z,|x|^2)
#define OFF_WLCNT 486656          // int[1] tail worklist count
#define OFF_WL 486784             // int[16384] tail worklist

__device__ __forceinline__ int cell1(float x) {
    int c = (int)floorf((x - BOX_LO) * INV_CELL);
    return min(max(c, 0), G - 1);
}

__device__ __forceinline__ void ins3(float v, int vi,
                                     float& s1, float& s2, float& s3,
                                     int& i1, int& i2, int& i3)
{
    const bool b1 = v < s1, b2 = v < s2, b3 = v < s3;
    s3 = b2 ? s2 : (b3 ? v : s3);   i3 = b2 ? i2 : (b3 ? vi : i3);
    s2 = b1 ? s1 : (b2 ? v : s2);   i2 = b1 ? i1 : (b2 ? vi : i2);
    s1 = b1 ? v : s1;               i1 = b1 ? vi : i1;
}

__device__ __forceinline__ void epilogue(float s1, float s2, float s3,
                                         int i1, int i2, int i3,
                                         const float4* __restrict__ ctx4s,
                                         const float* __restrict__ cnoise,
                                         float* __restrict__ out, int ai)
{
    const float d1 = sqrtf(fmaxf(s1, 0.0f) + 1e-12f);
    const float d2 = sqrtf(fmaxf(s2, 0.0f) + 1e-12f);
    const float d3 = sqrtf(fmaxf(s3, 0.0f) + 1e-12f);
    float w1 = 1.0f / (d1 + 1e-8f);
    float w2 = 1.0f / (d2 + 1e-8f);
    float w3 = 1.0f / (d3 + 1e-8f);
    float wsum = w1 + w2;
    wsum += w3;
    w1 /= wsum; w2 /= wsum; w3 /= wsum;
    const float4 c1 = ctx4s[i1];
    const float4 c2 = ctx4s[i2];
    const float4 c3 = ctx4s[i3];
    float cxo = w1 * c1.x + w2 * c2.x; cxo += w3 * c3.x;
    float cyo = w1 * c1.y + w2 * c2.y; cyo += w3 * c3.y;
    float czo = w1 * c1.z + w2 * c2.z; czo += w3 * c3.z;
    out[3 * ai + 0] = cxo + 0.5f * cnoise[3 * ai + 0];
    out[3 * ai + 1] = cyo + 0.5f * cnoise[3 * ai + 1];
    out[3 * ai + 2] = czo + 0.5f * cnoise[3 * ai + 2];
}

// K1: classify + base_noise + gen flags + per-atom cell id (no atomics)
__global__ __launch_bounds__(NTHR)
void k1_classify(const float* __restrict__ X,
                 const int* __restrict__ block_ids,
                 const unsigned int* __restrict__ mask,
                 const float* __restrict__ base_noise,
                 float* __restrict__ out,
                 unsigned long long* __restrict__ flags,
                 int* __restrict__ blk_gen,
                 unsigned short* __restrict__ acell,
                 int* __restrict__ wl_cnt)
{
    __shared__ int sflag;
    __shared__ int wg[4];
    const int t = threadIdx.x;
    const int wave = t >> 6, lane = t & 63;
    if (blockIdx.x == 0 && t == 0) wl_cnt[0] = 0;

    // mask dtype probe: int32 0/1 values vs packed bool bytes (R2-R15 validated)
    if (t == 0) sflag = 0;
    __syncthreads();
    if (mask[t] > 1u) sflag = 1;    // benign same-value race
    __syncthreads();
    const bool is_u8 = (sflag != 0);
    const unsigned char* m8 = (const unsigned char*)mask;

    const int i = blockIdx.x * NTHR + t;
    const int bid = block_ids[i];
    const bool g = is_u8 ? (m8[bid] != 0) : (mask[bid] != 0u);

    out[3 * i + 0] = base_noise[3 * i + 0];
    out[3 * i + 1] = base_noise[3 * i + 1];
    out[3 * i + 2] = base_noise[3 * i + 2];

    const unsigned long long mg = __ballot(g);
    if (lane == 0) { flags[blockIdx.x * 4 + wave] = mg; wg[wave] = __popcll(mg); }
    __syncthreads();
    if (t == 0) blk_gen[blockIdx.x] = wg[0] + wg[1] + wg[2] + wg[3];

    unsigned short c = 0xFFFFu;
    if (!g) {
        const float x = X[3 * i], y = X[3 * i + 1], z = X[3 * i + 2];
        c = (unsigned short)((cell1(z) * G + cell1(y)) * G + cell1(x));
    }
    acell[i] = c;
}

// K2: single-block LDS counting sort: histogram -> scan -> positions.
__global__ __launch_bounds__(1024)
void k2_sort(const unsigned short* __restrict__ acell,
             int* __restrict__ cell_start,
             int* __restrict__ pos,
             const int* __restrict__ blk_gen,
             int* __restrict__ blk_goff,
             int* __restrict__ counts)
{
    __shared__ int hist[NCELLS_PAD];          // 57,344 B
    __shared__ int wsum[16], wexc[16];
    const int t = threadIdx.x;
    const int wave = t >> 6, lane = t & 63;

    #pragma unroll
    for (int k = 0; k < CPT; ++k) hist[t * CPT + k] = 0;
    __syncthreads();

    #pragma unroll
    for (int it = 0; it < N_ATOMS / 1024; ++it) {
        const unsigned short c = acell[it * 1024 + t];
        if (c != 0xFFFFu) atomicAdd(&hist[c], 1);
    }
    __syncthreads();

    int loc[CPT]; int sum = 0;
    #pragma unroll
    for (int k = 0; k < CPT; ++k) {
        const int v = hist[t * CPT + k];
        loc[k] = sum; sum += v;
    }
    int v = sum;
    #pragma unroll
    for (int d = 1; d < 64; d <<= 1) { const int u = __shfl_up(v, d); if (lane >= d) v += u; }
    if (lane == 63) wsum[wave] = v;
    __syncthreads();
    if (t < 16) {
        int v2 = wsum[t];
        const int orig = v2;
        #pragma unroll
        for (int d = 1; d < 16; d <<= 1) { const int u = __shfl_up(v2, d); if (t >= d) v2 += u; }
        wexc[t] = v2 - orig;
    }
    __syncthreads();
    const int base = wexc[wave] + (v - sum);
    #pragma unroll
    for (int k = 0; k < CPT; ++k) {
        const int st = base + loc[k];
        cell_start[t * CPT + k] = st;
        hist[t * CPT + k] = st;               // -> cursor
    }
    if (t == 1023) cell_start[NCELLS_PAD] = base + sum;
    __syncthreads();

    #pragma unroll
    for (int it = 0; it < N_ATOMS / 1024; ++it) {
        const int i = it * 1024 + t;
        const unsigned short c = acell[i];
        if (c != 0xFFFFu) pos[i] = atomicAdd(&hist[c], 1);
    }

    if (t < 64) {
        const int o = blk_gen[t];
        int s = o;
        #pragma unroll
        for (int d = 1; d < 64; d <<= 1) { const int u = __shfl_up(s, d); if (t >= d) s += u; }
        blk_goff[t] = s - o;
        if (t == 63) { counts[1] = s; counts[0] = N_ATOMS - s; }
    }
}

// K3: scatter (no atomics)
__global__ __launch_bounds__(NTHR)
void k3_scatter(const float* __restrict__ X,
                const unsigned long long* __restrict__ flags,
                const int* __restrict__ blk_goff,
                const int* __restrict__ pos,
                float4* __restrict__ ctx4s,
                int* __restrict__ genidx)
{
    const int t = threadIdx.x;
    const int wave = t >> 6, lane = t & 63;
    const int i = blockIdx.x * NTHR + t;
    const unsigned long long fw = flags[blockIdx.x * 4 + wave];
    const bool g = (fw >> lane) & 1ull;
    if (g) {
        int og = blk_goff[blockIdx.x];
        #pragma unroll
        for (int w = 0; w < 4; ++w) {
            if (w < wave) og += __popcll(flags[blockIdx.x * 4 + w]);
        }
        const unsigned long long below = (1ull << lane) - 1ull;
        og += __popcll(fw & below);
        genidx[og] = i;
    } else {
        const float x = X[3 * i], y = X[3 * i + 1], z = X[3 * i + 2];
        float xn = x * x; xn += y * y; xn += z * z;
        ctx4s[pos[i]] = make_float4(x, y, z, xn);
    }
}

// K4a: BULK — phase A (r<=1 box) only; non-converged atoms -> worklist.
__global__ __launch_bounds__(NTHR)
void k4a_bulk(const float* __restrict__ X,
              const float* __restrict__ cnoise,
              const int* __restrict__ counts,
              const int* __restrict__ cell_start,
              const float4* __restrict__ ctx4s,
              const int* __restrict__ genidx,
              float* __restrict__ out,
              int* __restrict__ wl_cnt,
              int* __restrict__ wl)
{
    const int n_gen = counts[1];
    const int wave = threadIdx.x >> 6, lane = threadIdx.x & 63;
    if ((int)blockIdx.x * 4 >= n_gen) return;
    const int slot = (int)blockIdx.x * 4 + wave;
    if (slot >= n_gen) return;

    const int ai = genidx[slot];
    const float qx = X[3 * ai], qy = X[3 * ai + 1], qz = X[3 * ai + 2];
    float xnq = qx * qx; xnq += qy * qy; xnq += qz * qz;
    const int cqx = cell1(qx), cqy = cell1(qy), cqz = cell1(qz);

    float s1 = SINIT, s2 = SINIT, s3 = SINIT;
    int i1 = 0, i2 = 0, i3 = 0;

    // phase A: r<=1 box as 9 row-segments, shuffle-free scan (R13 proven)
    {
        int st = 0, cnt = 0;
        if (lane < 9) {
            const int dy = lane % 3 - 1, dz = lane / 3 - 1;
            const int cy = cqy + dy, cz = cqz + dz;
            if ((unsigned)cy < G && (unsigned)cz < G) {
                const int xlo = max(cqx - 1, 0), xhi = min(cqx + 1, G - 1);
                const int c0 = (cz * G + cy) * G + xlo;
                st = cell_start[c0];
                cnt = cell_start[c0 + (xhi - xlo + 1)] - st;
            }
        }
        int stv[9], base[10];
        base[0] = 0;
        #pragma unroll
        for (int k = 0; k < 9; ++k) {
            stv[k] = __builtin_amdgcn_readlane(st, k);
            base[k + 1] = base[k] + __builtin_amdgcn_readlane(cnt, k);
        }
        const int T = base[9];
        const int nro = (T + 63) >> 6;
        if (nro > 0) {
            auto calcP = [&](int j) -> int {
                const int jc = min(j, T - 1);
                int p = stv[0] + jc;
                #pragma unroll
                for (int k = 1; k < 9; ++k)
                    p = (jc >= base[k]) ? stv[k] + (jc - base[k]) : p;
                return p;
            };
            int p0 = calcP(lane);
            float4 cc0 = ctx4s[p0];
            for (int ro = 0; ro < nro; ++ro) {
                int p1 = p0; float4 cc1 = cc0;
                if (ro + 1 < nro) { p1 = calcP((ro + 1) * 64 + lane); cc1 = ctx4s[p1]; }
                if (ro * 64 + lane < T) {
                    const float dot = qx * cc0.x + qy * cc0.y + qz * cc0.z;
                    const float sq = (xnq + cc0.w) - 2.0f * dot;
                    ins3(sq, p0, s1, s2, s3, i1, i2, i3);
                }
                p0 = p1; cc0 = cc1;
            }
        }
    }

    // ballot-count convergence (== merged-m3 + 0.01 < 16)
    const int cb = __popcll(__ballot(s1 + 0.01f < 16.0f))
                 + __popcll(__ballot(s2 + 0.01f < 16.0f))
                 + __popcll(__ballot(s3 + 0.01f < 16.0f));
    if (cb < 3) {
        if (lane == 0) { const int w = atomicAdd(wl_cnt, 1); wl[w] = slot; }
        return;
    }

    #pragma unroll
    for (int m = 1; m < 64; m <<= 1) {
        const float a = __shfl_xor(s1, m); const int ja = __shfl_xor(i1, m);
        const float b = __shfl_xor(s2, m); const int jb = __shfl_xor(i2, m);
        const float c = __shfl_xor(s3, m); const int jc = __shfl_xor(i3, m);
        ins3(a, ja, s1, s2, s3, i1, i2, i3);
        ins3(b, jb, s1, s2, s3, i1, i2, i3);
        ins3(c, jc, s1, s2, s3, i1, i2, i3);
    }
    if (lane == 0) epilogue(s1, s2, s3, i1, i2, i3, ctx4s, cnoise, out, ai);
}

// K4b: TAIL — one block (4 waves) per worklist atom, cooperative rings.
__global__ __launch_bounds__(NTHR)
void k4b_tail(const float* __restrict__ X,
              const float* __restrict__ cnoise,
              const int* __restrict__ counts,
              const int* __restrict__ cell_start,
              const float4* __restrict__ ctx4s,
              const int* __restrict__ genidx,
              float* __restrict__ out,
              const int* __restrict__ wl_cnt,
              const int* __restrict__ wl)
{
    __shared__ int cnts[4];
    __shared__ int dflag;
    __shared__ int mrg[24];
    const int t = threadIdx.x;
    const int wave = t >> 6, lane = t & 63;
    const int count = wl_cnt[0];

    for (int wid = blockIdx.x; wid < count; wid += gridDim.x) {
        const int slot = wl[wid];
        const int ai = genidx[slot];
        const float qx = X[3 * ai], qy = X[3 * ai + 1], qz = X[3 * ai + 2];
        float xnq = qx * qx; xnq += qy * qy; xnq += qz * qz;
        const int cqx = cell1(qx), cqy = cell1(qy), cqz = cell1(qz);

        float s1 = SINIT, s2 = SINIT, s3 = SINIT;
        int i1 = 0, i2 = 0, i3 = 0;

        auto searchOwner = [&](int ebase_r, int jc) -> int {
            int L = 0;
            #pragma unroll
            for (int stp = 32; stp >= 1; stp >>= 1) {
                const int cand = L + stp;
                const int bv = __shfl(ebase_r, cand);
                if (bv <= jc) L = cand;
            }
            return L;
        };
        auto flatScan = [&](int T, int ebase_r, int pk_r) {
            const int iters = (T + 63) >> 6;
            for (int it = 0; it < iters; ++it) {
                const int j = it * 64 + lane;
                const int jc = min(j, T - 1);
                const int p = __shfl(pk_r, searchOwner(ebase_r, jc)) + jc;
                const float4 cc = ctx4s[p];
                if (j < T) {
                    const float dot = qx * cc.x + qy * cc.y + qz * cc.z;
                    const float sq = (xnq + cc.w) - 2.0f * dot;
                    ins3(sq, p, s1, s2, s3, i1, i2, i3);
                }
            }
        };
        auto prefixT = [&](int cnt, int& ebase_r, int& T) {
            int pre = cnt;
            #pragma unroll
            for (int d = 1; d < 64; d <<= 1) {
                const int u = __shfl_up(pre, d);
                if (lane >= d) pre += u;
            }
            T = __shfl(pre, 63);
            ebase_r = pre - cnt;
        };

        // phase A split: wave w owns rows {w, w+4, w+8} (disjoint)
        {
            int st = 0, cnt = 0;
            const int ru = wave + 4 * lane;        // lane 0..2
            if (lane < 3 && ru < 9) {
                const int dy = ru % 3 - 1, dz = ru / 3 - 1;
                const int cy = cqy + dy, cz = cqz + dz;
                if ((unsigned)cy < G && (unsigned)cz < G) {
                    const int xlo = max(cqx - 1, 0), xhi = min(cqx + 1, G - 1);
                    const int c0 = (cz * G + cy) * G + xlo;
                    st = cell_start[c0];
                    cnt = cell_start[c0 + (xhi - xlo + 1)] - st;
                }
            }
            int stv[3], base[4];
            base[0] = 0;
            #pragma unroll
            for (int k = 0; k < 3; ++k) {
                stv[k] = __builtin_amdgcn_readlane(st, k);
                base[k + 1] = base[k] + __builtin_amdgcn_readlane(cnt, k);
            }
            const int T = base[3];
            for (int j = lane; j < T; j += 64) {
                int p = stv[0] + j;
                #pragma unroll
                for (int k = 1; k < 3; ++k)
                    p = (j >= base[k]) ? stv[k] + (j - base[k]) : p;
                const float4 cc = ctx4s[p];
                const float dot = qx * cc.x + qy * cc.y + qz * cc.z;
                const float sq = (xnq + cc.w) - 2.0f * dot;
                ins3(sq, p, s1, s2, s3, i1, i2, i3);
            }
        }

        auto blockConv = [&](float bnd) -> bool {
            const int c = __popcll(__ballot(s1 + 0.01f < bnd))
                        + __popcll(__ballot(s2 + 0.01f < bnd))
                        + __popcll(__ballot(s3 + 0.01f < bnd));
            if (lane == 0) cnts[wave] = c;
            __syncthreads();
            if (t == 0) dflag = (cnts[0] + cnts[1] + cnts[2] + cnts[3] >= 3);
            __syncthreads();
            return dflag != 0;
        };

        bool done = blockConv(16.0f);

        // ring levels (P,R] = (1,2],(2,4],(4,8]; rounds round-robin over waves
        for (int li = 1; li < 4; ++li) {
            if (!done) {
                const int P = 1 << (li - 1), R = 1 << li;
                const int B = 2 * R + 1;
                const int RP = R - P;
                const int PP = 2 * P + 1;
                const int A = 2 * RP * B;
                const int C = PP * 2 * RP;
                const int NS = A + C + 2 * PP * PP;
                const int nro = (NS + 63) >> 6;
                for (int ro = wave; ro < nro; ro += 4) {
                    const int u = ro * 64 + lane;
                    int st = 0, cnt = 0;
                    if (u < NS) {
                        int dy, dz, xlo, xhi;
                        if (u < A) {
                            const int q = u / B, rdy = u - q * B;
                            dz = (q < RP) ? (-R + q) : (P + 1 + (q - RP));
                            dy = rdy - R;
                            xlo = cqx - R; xhi = cqx + R;
                        } else if (u < A + C) {
                            const int v = u - A, W = 2 * RP;
                            const int q = v / W, w = v - q * W;
                            dz = -P + q;
                            dy = (w < RP) ? (-R + w) : (P + 1 + (w - RP));
                            xlo = cqx - R; xhi = cqx + R;
                        } else {
                            const int v = u - A - C;
                            const int side = v & 1, v2 = v >> 1;
                            dy = v2 % PP - P; dz = v2 / PP - P;
                            if (side) { xlo = cqx + P + 1; xhi = cqx + R; }
                            else      { xlo = cqx - R;     xhi = cqx - P - 1; }
                        }
                        const int cy = cqy + dy, cz = cqz + dz;
                        if ((unsigned)cy < G && (unsigned)cz < G) {
                            xlo = max(xlo, 0); xhi = min(xhi, G - 1);
                            if (xlo <= xhi) {
                                const int c0 = (cz * G + cy) * G + xlo;
                                st = cell_start[c0];
                                cnt = cell_start[c0 + (xhi - xlo + 1)] - st;
                            }
                        }
                    }
                    int eb, Tr;
                    prefixT(cnt, eb, Tr);
                    if (Tr > 0) flatScan(Tr, eb, st - eb);
                }
                done = blockConv((float)(4 * R) * (float)(4 * R));
            }
        }
        if (!done) {
            // exhaustive restart, block-cooperative (exact, duplicate-free)
            s1 = SINIT; s2 = SINIT; s3 = SINIT;
            i1 = 0; i2 = 0; i3 = 0;
            const int n_ctx = counts[0];
            for (int bse = 0; bse < n_ctx; bse += NTHR) {
                const int p = bse + t;
                if (p < n_ctx) {
                    const float4 cc = ctx4s[p];
                    const float dot = qx * cc.x + qy * cc.y + qz * cc.z;
                    const float sq = (xnq + cc.w) - 2.0f * dot;
                    ins3(sq, p, s1, s2, s3, i1, i2, i3);
                }
            }
        }

        // per-wave index merge, then 12-way LDS merge + epilogue
        #pragma unroll
        for (int m = 1; m < 64; m <<= 1) {
            const float a = __shfl_xor(s1, m); const int ja = __shfl_xor(i1, m);
            const float b = __shfl_xor(s2, m); const int jb = __shfl_xor(i2, m);
            const float c = __shfl_xor(s3, m); const int jc = __shfl_xor(i3, m);
            ins3(a, ja, s1, s2, s3, i1, i2, i3);
            ins3(b, jb, s1, s2, s3, i1, i2, i3);
            ins3(c, jc, s1, s2, s3, i1, i2, i3);
        }
        if (lane == 0) {
            mrg[wave * 6 + 0] = __float_as_int(s1);
            mrg[wave * 6 + 1] = __float_as_int(s2);
            mrg[wave * 6 + 2] = __float_as_int(s3);
            mrg[wave * 6 + 3] = i1;
            mrg[wave * 6 + 4] = i2;
            mrg[wave * 6 + 5] = i3;
        }
        __syncthreads();
        if (t == 0) {
            float a1 = SINIT, a2 = SINIT, a3 = SINIT;
            int j1 = 0, j2 = 0, j3 = 0;
            #pragma unroll
            for (int w = 0; w < 4; ++w) {
                #pragma unroll
                for (int k = 0; k < 3; ++k) {
                    ins3(__int_as_float(mrg[w * 6 + k]), mrg[w * 6 + 3 + k],
                         a1, a2, a3, j1, j2, j3);
                }
            }
            epilogue(a1, a2, a3, j1, j2, j3, ctx4s, cnoise, out, ai);
        }
        __syncthreads();   // protect mrg/cnts before next worklist atom
    }
}

extern "C" void kernel_launch(void* const* d_in, const int* in_sizes, int n_in,
                              void* d_out, int out_size, void* d_ws, size_t ws_size,
                              hipStream_t stream) {
    const float* X          = (const float*)d_in[0];
    const float* base_noise = (const float*)d_in[1];
    const float* cnoise     = (const float*)d_in[2];
    const int*   block_ids  = (const int*)d_in[3];
    const unsigned int* gmask = (const unsigned int*)d_in[4];
    float* out = (float*)d_out;

    char* ws = (char*)d_ws;
    int*    counts     = (int*)(ws + OFF_COUNTS);
    int*    blk_gen    = (int*)(ws + OFF_BLKGEN);
    int*    blk_goff   = (int*)(ws + OFF_BLKGOFF);
    unsigned long long* flags = (unsigned long long*)(ws + OFF_FLAGS);
    unsigned short* acell = (unsigned short*)(ws + OFF_ACELL);
    int*    pos        = (int*)(ws + OFF_POS);
    int*    cell_start = (int*)(ws + OFF_START);
    int*    genidx     = (int*)(ws + OFF_GENIDX);
    float4* ctx4s      = (float4*)(ws + OFF_CTX4);
    int*    wl_cnt     = (int*)(ws + OFF_WLCNT);
    int*    wl         = (int*)(ws + OFF_WL);

    k1_classify<<<NBLK, NTHR, 0, stream>>>(X, block_ids, gmask, base_noise,
                                           out, flags, blk_gen, acell, wl_cnt);
    k2_sort<<<1, 1024, 0, stream>>>(acell, cell_start, pos, blk_gen, blk_goff, counts);
    k3_scatter<<<NBLK, NTHR, 0, stream>>>(X, flags, blk_goff, pos, ctx4s, genidx);
    k4a_bulk<<<N_ATOMS / 4, NTHR, 0, stream>>>(X, cnoise, counts, cell_start,
                                               ctx4s, genidx, out, wl_cnt, wl);
    k4b_tail<<<1024, NTHR, 0, stream>>>(X, cnoise, counts, cell_start,
                                        ctx4s, genidx, out, wl_cnt, wl);
}